// Round 4
// baseline (189.935 us; speedup 1.0000x reference)
//
#include <hip/hip_runtime.h>
#include <hip/hip_fp16.h>
#include <math.h>

typedef __attribute__((ext_vector_type(8))) _Float16 half8;
typedef __attribute__((ext_vector_type(2))) __fp16 fp16x2;   // cvt_pkrtz result type
typedef __attribute__((ext_vector_type(4))) float float4v;

#define MFMA_F16 __builtin_amdgcn_mfma_f32_16x16x32_f16

// One block per (m, n1) row: 1024 points, masked softmax over them.
// 4 waves x 64 lanes; each wave owns 256 points in 16 tiles of 16.
// Layer1 (3->64, fp32 VALU) writes straight into fp16 MFMA A-fragments.
// Layer2 (64->64) = 8x mfma_f32_16x16x32_f16 per tile, b2 folded into C-in.
// Layer3 (64->1) fp32 VALU + 16-lane shfl reduce. b3 cancels in softmax.
__global__ __launch_bounds__(256, 2) void mlp_softmax_kernel(
    const float* __restrict__ diff, const int* __restrict__ mask,
    const float* __restrict__ W1, const float* __restrict__ b1,
    const float* __restrict__ W2, const float* __restrict__ b2,
    const float* __restrict__ W3, float* __restrict__ out)
{
    __shared__ float s_diff[3072];   // 1024 points x 3
    __shared__ float s_w2[4096];     // 64x64 row-major [k][n]
    __shared__ float s_w1[192];      // [d][h] 3x64
    __shared__ float s_b1[64];
    __shared__ float s_b2[64];
    __shared__ float s_w3[64];
    __shared__ float s_dots[1024];
    __shared__ float s_red[8];

    const int tid = threadIdx.x;
    const int bid = blockIdx.x;                  // m*1024 + n1
    const long row_off = (long)bid * 3072;

    // ---- stage row + weights (coalesced float4) ----
    {
        const float4v* gd = (const float4v*)(diff + row_off);
        float4v* sd = (float4v*)s_diff;
        #pragma unroll
        for (int it = 0; it < 3; ++it) sd[tid + 256 * it] = gd[tid + 256 * it];
        const float4v* gw2 = (const float4v*)W2;
        float4v* sw2 = (float4v*)s_w2;
        #pragma unroll
        for (int it = 0; it < 4; ++it) sw2[tid + 256 * it] = gw2[tid + 256 * it];
        if (tid < 48)                    ((float4v*)s_w1)[tid]      = ((const float4v*)W1)[tid];
        else if (tid >= 64 && tid < 80)  ((float4v*)s_b1)[tid - 64] = ((const float4v*)b1)[tid - 64];
        else if (tid >= 80 && tid < 96)  ((float4v*)s_b2)[tid - 80] = ((const float4v*)b2)[tid - 80];
        else if (tid >= 96 && tid < 112) ((float4v*)s_w3)[tid - 96] = ((const float4v*)W3)[tid - 96];
    }
    __syncthreads();

    const int lane = tid & 63;
    const int wv   = tid >> 6;
    const int lg   = lane >> 4;   // 0..3  (k-group / C-row group)
    const int lr   = lane & 15;   // 0..15 (A-row / C-col)

    // ---- hoist per-lane weight fragments into registers ----
    // Layer1 weights for this lane's 16 h-indices: h = kh*32 + lg*8 + e
    float w1r[2][3][8], b1r[2][8];
    #pragma unroll
    for (int kh = 0; kh < 2; ++kh) {
        const int hb = kh * 32 + lg * 8;
        #pragma unroll
        for (int e = 0; e < 8; ++e) {
            b1r[kh][e] = s_b1[hb + e];
            #pragma unroll
            for (int d = 0; d < 3; ++d) w1r[kh][d][e] = s_w1[d * 64 + hb + e];
        }
    }
    // W2 B-fragments: frag elem e -> W2[kh*32 + lg*8 + e][nt*16 + lr]
    half8 bfr[4][2];
    #pragma unroll
    for (int nt = 0; nt < 4; ++nt) {
        #pragma unroll
        for (int kh = 0; kh < 2; ++kh) {
            union { fp16x2 h2[4]; half8 h8; } u;
            #pragma unroll
            for (int ep = 0; ep < 4; ++ep) {
                const int k0 = kh * 32 + lg * 8 + ep * 2;
                const float f0 = s_w2[(k0    ) * 64 + nt * 16 + lr];
                const float f1 = s_w2[(k0 + 1) * 64 + nt * 16 + lr];
                u.h2[ep] = __builtin_amdgcn_cvt_pkrtz(f0, f1);
            }
            bfr[nt][kh] = u.h8;
        }
    }
    float b2r[4], w3r[4];
    #pragma unroll
    for (int nt = 0; nt < 4; ++nt) {
        b2r[nt] = s_b2[nt * 16 + lr];
        w3r[nt] = s_w3[nt * 16 + lr];
    }

    // ---- main loop: 16 tiles of 16 points per wave ----
    const int jw0 = wv * 256;
    for (int t = 0; t < 16; ++t) {
        const int j0 = jw0 + t * 16;
        const int jp = j0 + lr;                 // this lane's A-row point
        const float x0 = s_diff[jp * 3 + 0];
        const float x1 = s_diff[jp * 3 + 1];
        const float x2 = s_diff[jp * 3 + 2];

        half8 afr[2];
        #pragma unroll
        for (int kh = 0; kh < 2; ++kh) {
            union { fp16x2 h2[4]; half8 h8; } u;
            #pragma unroll
            for (int ep = 0; ep < 4; ++ep) {
                const int e0 = ep * 2, e1 = ep * 2 + 1;
                float h0 = fmaf(x2, w1r[kh][2][e0],
                           fmaf(x1, w1r[kh][1][e0],
                           fmaf(x0, w1r[kh][0][e0], b1r[kh][e0])));
                float h1 = fmaf(x2, w1r[kh][2][e1],
                           fmaf(x1, w1r[kh][1][e1],
                           fmaf(x0, w1r[kh][0][e1], b1r[kh][e1])));
                h0 = fmaxf(h0, 0.0f);
                h1 = fmaxf(h1, 0.0f);
                u.h2[ep] = __builtin_amdgcn_cvt_pkrtz(h0, h1);
            }
            afr[kh] = u.h8;
        }

        float sr[4] = {0.f, 0.f, 0.f, 0.f};
        #pragma unroll
        for (int nt = 0; nt < 4; ++nt) {
            float4v acc = {b2r[nt], b2r[nt], b2r[nt], b2r[nt]};  // bias via C-in
            acc = MFMA_F16(afr[0], bfr[nt][0], acc, 0, 0, 0);
            acc = MFMA_F16(afr[1], bfr[nt][1], acc, 0, 0, 0);
            #pragma unroll
            for (int r = 0; r < 4; ++r)
                sr[r] = fmaf(fmaxf(acc[r], 0.0f), w3r[nt], sr[r]);
        }
        // reduce over the 16 C-columns (lr dimension)
        #pragma unroll
        for (int off = 1; off < 16; off <<= 1) {
            #pragma unroll
            for (int r = 0; r < 4; ++r) sr[r] += __shfl_xor(sr[r], off, 64);
        }
        if (lr == 0) {
            #pragma unroll
            for (int r = 0; r < 4; ++r) s_dots[j0 + lg * 4 + r] = sr[r];
        }
    }
    __syncthreads();

    // ---- masked softmax over the 1024 points ----
    const int j4 = tid * 4;
    float4v dv = *(const float4v*)&s_dots[j4];
    const int4 mv = *(const int4*)(mask + (long)bid * 1024 + j4);
    const float NINF = -__builtin_inff();
    float d0 = mv.x ? NINF : dv[0];
    float d1 = mv.y ? NINF : dv[1];
    float d2 = mv.z ? NINF : dv[2];
    float d3 = mv.w ? NINF : dv[3];

    float mx = fmaxf(fmaxf(d0, d1), fmaxf(d2, d3));
    #pragma unroll
    for (int off = 1; off < 64; off <<= 1) mx = fmaxf(mx, __shfl_xor(mx, off, 64));
    if (lane == 0) s_red[wv] = mx;
    __syncthreads();
    mx = fmaxf(fmaxf(s_red[0], s_red[1]), fmaxf(s_red[2], s_red[3]));

    const float e0 = mv.x ? 0.0f : __expf(d0 - mx);
    const float e1 = mv.y ? 0.0f : __expf(d1 - mx);
    const float e2 = mv.z ? 0.0f : __expf(d2 - mx);
    const float e3 = mv.w ? 0.0f : __expf(d3 - mx);
    float s = (e0 + e1) + (e2 + e3);
    #pragma unroll
    for (int off = 1; off < 64; off <<= 1) s += __shfl_xor(s, off, 64);
    if (lane == 0) s_red[4 + wv] = s;
    __syncthreads();
    const float tot = (s_red[4] + s_red[5]) + (s_red[6] + s_red[7]);
    const float inv = 1.0f / tot;

    float4v ov = {e0 * inv, e1 * inv, e2 * inv, e3 * inv};
    *(float4v*)(out + (long)bid * 1024 + j4) = ov;
}

extern "C" void kernel_launch(void* const* d_in, const int* in_sizes, int n_in,
                              void* d_out, int out_size, void* d_ws, size_t ws_size,
                              hipStream_t stream) {
    const float* diff = (const float*)d_in[0];
    const int*   mask = (const int*)d_in[1];
    const float* W1   = (const float*)d_in[2];
    const float* b1   = (const float*)d_in[3];
    const float* W2   = (const float*)d_in[4];
    const float* b2   = (const float*)d_in[5];
    const float* W3   = (const float*)d_in[6];
    // b3 (d_in[7]) cancels in softmax -> unused
    float* out = (float*)d_out;

    mlp_softmax_kernel<<<dim3(4096), dim3(256), 0, stream>>>(
        diff, mask, W1, b1, W2, b2, W3, out);
}

// Round 6
// 169.943 us; speedup vs baseline: 1.1176x; 1.1176x over previous
//
#include <hip/hip_runtime.h>
#include <hip/hip_fp16.h>
#include <math.h>

typedef __attribute__((ext_vector_type(8))) _Float16 half8;
typedef __attribute__((ext_vector_type(2))) __fp16 fp16x2;   // cvt_pkrtz result type
typedef __attribute__((ext_vector_type(4))) float float4v;
typedef __attribute__((ext_vector_type(2))) float float2v;

#define MFMA_F16 __builtin_amdgcn_mfma_f32_16x16x32_f16

// One block per (m, n1) row: 1024 points, masked softmax over them.
// 4 waves x 64 lanes; each wave owns 256 points in 16 tiles of 16.
// Layer1 (3->64) in packed fp32 (v_pk_fma_f32) writing fp16 MFMA fragments.
// Layer2: OPERAND-SWAPPED mfma(A=W2^T, B=h1) -> D[h_out][point]; each lane
//   holds 16 h_out partials for ONE point, so the layer-3 reduce is just
//   shfl_xor 16 + 32 (2 ops) instead of a 4-deep chain over 4 regs.
// Layer3 (64->1) packed fp32 relu-dot. b3 cancels in softmax.
// s_w2 LDS is reused as s_dots after fragment setup (barrier-protected).
__global__ __launch_bounds__(256, 2) void mlp_softmax_kernel(
    const float* __restrict__ diff, const int* __restrict__ mask,
    const float* __restrict__ W1, const float* __restrict__ b1,
    const float* __restrict__ W2, const float* __restrict__ b2,
    const float* __restrict__ W3, float* __restrict__ out)
{
    __shared__ float s_diff[3072];   // 1024 points x 3
    __shared__ float s_w2[4096];     // 64x64 [k][n]; reused as s_dots later
    __shared__ float s_w1[192];      // [d][h] 3x64
    __shared__ float s_b1[64];
    __shared__ float s_b2[64];
    __shared__ float s_w3[64];
    __shared__ float s_red[8];

    float* const s_dots = s_w2;      // overlay: s_w2 dead after setup

    const int tid = threadIdx.x;
    const int bid = blockIdx.x;                  // m*1024 + n1
    const long row_off = (long)bid * 3072;

    // ---- stage row + weights (coalesced float4) ----
    {
        const float4v* gd = (const float4v*)(diff + row_off);
        float4v* sd = (float4v*)s_diff;
        #pragma unroll
        for (int it = 0; it < 3; ++it) sd[tid + 256 * it] = gd[tid + 256 * it];
        const float4v* gw2 = (const float4v*)W2;
        float4v* sw2 = (float4v*)s_w2;
        #pragma unroll
        for (int it = 0; it < 4; ++it) sw2[tid + 256 * it] = gw2[tid + 256 * it];
        if (tid < 48)                    ((float4v*)s_w1)[tid]      = ((const float4v*)W1)[tid];
        else if (tid >= 64 && tid < 80)  ((float4v*)s_b1)[tid - 64] = ((const float4v*)b1)[tid - 64];
        else if (tid >= 80 && tid < 96)  ((float4v*)s_b2)[tid - 80] = ((const float4v*)b2)[tid - 80];
        else if (tid >= 96 && tid < 112) ((float4v*)s_w3)[tid - 96] = ((const float4v*)W3)[tid - 96];
    }
    __syncthreads();

    const int lane = tid & 63;
    const int wv   = tid >> 6;
    const int lg   = lane >> 4;   // 0..3  lane group
    const int lr   = lane & 15;   // 0..15

    // ---- hoist per-lane weight fragments ----
    // Layer1: this lane's 16 h-indices are h = kh*32 + lg*8 + e, as 8 pairs.
    const int hb0 = lg * 8;
    float2v w1p[2][3][4], b1p[2][4];
    #pragma unroll
    for (int kh = 0; kh < 2; ++kh) {
        const int hb = kh * 32 + hb0;
        #pragma unroll
        for (int p = 0; p < 4; ++p) {
            b1p[kh][p] = *(const float2v*)&s_b1[hb + 2 * p];
            #pragma unroll
            for (int d = 0; d < 3; ++d)
                w1p[kh][d][p] = *(const float2v*)&s_w1[d * 64 + hb + 2 * p];
        }
    }
    // W2^T A-fragments: elem e -> W2[kh*32 + lg*8 + e][nt*16 + lr]
    half8 bfr[4][2];
    #pragma unroll
    for (int nt = 0; nt < 4; ++nt) {
        #pragma unroll
        for (int kh = 0; kh < 2; ++kh) {
            union { fp16x2 h2[4]; half8 h8; } u;
            #pragma unroll
            for (int ep = 0; ep < 4; ++ep) {
                const int k0 = kh * 32 + lg * 8 + ep * 2;
                const float f0 = s_w2[(k0    ) * 64 + nt * 16 + lr];
                const float f1 = s_w2[(k0 + 1) * 64 + nt * 16 + lr];
                u.h2[ep] = __builtin_amdgcn_cvt_pkrtz(f0, f1);
            }
            bfr[nt][kh] = u.h8;
        }
    }
    // Swapped D rows: h_out = nt*16 + lg*4 + r  -> bias & W3 per (nt, r)
    float4v b2v[4], w3v[4];
    #pragma unroll
    for (int nt = 0; nt < 4; ++nt) {
        b2v[nt] = *(const float4v*)&s_b2[nt * 16 + lg * 4];
        w3v[nt] = *(const float4v*)&s_w3[nt * 16 + lg * 4];
    }
    __syncthreads();   // all waves done reading s_w2 before s_dots overlay

    const float2v zero2 = {0.0f, 0.0f};
    const float4v zero4 = {0.0f, 0.0f, 0.0f, 0.0f};

    // ---- main loop: 16 tiles of 16 points per wave ----
    const int jw0 = wv * 256;
    for (int t = 0; t < 16; ++t) {
        const int j0 = jw0 + t * 16;
        const int jp = j0 + lr;                 // this lane's point (B-col)
        const float x0 = s_diff[jp * 3 + 0];
        const float x1 = s_diff[jp * 3 + 1];
        const float x2 = s_diff[jp * 3 + 2];
        const float2v x0p = {x0, x0}, x1p = {x1, x1}, x2p = {x2, x2};

        half8 afr[2];
        #pragma unroll
        for (int kh = 0; kh < 2; ++kh) {
            union { fp16x2 h2[4]; half8 h8; } u;
            #pragma unroll
            for (int p = 0; p < 4; ++p) {
                float2v h = b1p[kh][p];
                h = __builtin_elementwise_fma(x0p, w1p[kh][0][p], h);
                h = __builtin_elementwise_fma(x1p, w1p[kh][1][p], h);
                h = __builtin_elementwise_fma(x2p, w1p[kh][2][p], h);
                h = __builtin_elementwise_max(h, zero2);
                u.h2[p] = __builtin_amdgcn_cvt_pkrtz(h[0], h[1]);
            }
            afr[kh] = u.h8;
        }

        float2v sr2 = zero2;
        #pragma unroll
        for (int nt = 0; nt < 4; ++nt) {
            float4v acc = b2v[nt];                         // bias via C-in
            acc = MFMA_F16(bfr[nt][0], afr[0], acc, 0, 0, 0);  // A=W2^T, B=h1
            acc = MFMA_F16(bfr[nt][1], afr[1], acc, 0, 0, 0);
            const float4v rl = __builtin_elementwise_max(acc, zero4);
            const float2v rlo = {rl[0], rl[1]}, rhi = {rl[2], rl[3]};
            const float2v wlo = {w3v[nt][0], w3v[nt][1]};
            const float2v whi = {w3v[nt][2], w3v[nt][3]};
            sr2 = __builtin_elementwise_fma(rlo, wlo, sr2);
            sr2 = __builtin_elementwise_fma(rhi, whi, sr2);
        }
        float sr = sr2[0] + sr2[1];
        // combine the 4 lane-groups' h_out quarters for this point
        sr += __shfl_xor(sr, 16, 64);
        sr += __shfl_xor(sr, 32, 64);
        if (lane < 16) s_dots[j0 + lane] = sr;
    }
    __syncthreads();

    // ---- masked softmax over the 1024 points ----
    const int j4 = tid * 4;
    float4v dv = *(const float4v*)&s_dots[j4];
    const int4 mv = *(const int4*)(mask + (long)bid * 1024 + j4);
    const float NINF = -__builtin_inff();
    float d0 = mv.x ? NINF : dv[0];
    float d1 = mv.y ? NINF : dv[1];
    float d2 = mv.z ? NINF : dv[2];
    float d3 = mv.w ? NINF : dv[3];

    float mx = fmaxf(fmaxf(d0, d1), fmaxf(d2, d3));
    #pragma unroll
    for (int off = 1; off < 64; off <<= 1) mx = fmaxf(mx, __shfl_xor(mx, off, 64));
    if (lane == 0) s_red[wv] = mx;
    __syncthreads();
    mx = fmaxf(fmaxf(s_red[0], s_red[1]), fmaxf(s_red[2], s_red[3]));

    const float e0 = mv.x ? 0.0f : __expf(d0 - mx);
    const float e1 = mv.y ? 0.0f : __expf(d1 - mx);
    const float e2 = mv.z ? 0.0f : __expf(d2 - mx);
    const float e3 = mv.w ? 0.0f : __expf(d3 - mx);
    float s = (e0 + e1) + (e2 + e3);
    #pragma unroll
    for (int off = 1; off < 64; off <<= 1) s += __shfl_xor(s, off, 64);
    if (lane == 0) s_red[4 + wv] = s;
    __syncthreads();
    const float tot = (s_red[4] + s_red[5]) + (s_red[6] + s_red[7]);
    const float inv = 1.0f / tot;

    float4v ov = {e0 * inv, e1 * inv, e2 * inv, e3 * inv};
    *(float4v*)(out + (long)bid * 1024 + j4) = ov;
}

extern "C" void kernel_launch(void* const* d_in, const int* in_sizes, int n_in,
                              void* d_out, int out_size, void* d_ws, size_t ws_size,
                              hipStream_t stream) {
    const float* diff = (const float*)d_in[0];
    const int*   mask = (const int*)d_in[1];
    const float* W1   = (const float*)d_in[2];
    const float* b1   = (const float*)d_in[3];
    const float* W2   = (const float*)d_in[4];
    const float* b2   = (const float*)d_in[5];
    const float* W3   = (const float*)d_in[6];
    // b3 (d_in[7]) cancels in softmax -> unused
    float* out = (float*)d_out;

    mlp_softmax_kernel<<<dim3(4096), dim3(256), 0, stream>>>(
        diff, mask, W1, b1, W2, b2, W3, out);
}